// Round 6
// baseline (361.895 us; speedup 1.0000x reference)
//
#include <hip/hip_runtime.h>
#include <hip/hip_bf16.h>

typedef unsigned short u16;
typedef float f32x4 __attribute__((ext_vector_type(4)));
typedef __bf16 bf16x8 __attribute__((ext_vector_type(8)));
typedef __bf16 bf16x4 __attribute__((ext_vector_type(4)));
typedef unsigned short su8v __attribute__((ext_vector_type(8)));
typedef unsigned short su4v __attribute__((ext_vector_type(4)));
typedef short s16x4 __attribute__((ext_vector_type(4)));

#define BB 8
#define NHD 8
#define DD 128
#define NN 1024
#define DIM 1024
#define H3 3072
#define MM 8192
// scale * log2(e), folded into Q weights so softmax is exp2(raw dot)
#define QSC (0.08838834764831845f * 1.4426950408889634f)

__constant__ int   d_IDX[16] = {0,1,2,3, 1,0,3,2, 2,3,0,1, 3,2,1,0};
__constant__ float d_SGN[16] = {1.f,-1.f,-1.f,-1.f, 1.f,1.f,1.f,-1.f,
                                1.f,-1.f,1.f,1.f,  1.f,1.f,-1.f,1.f};

__device__ __forceinline__ f32x4 mfma16(su8v a, su8v b, f32x4 c) {
  return __builtin_amdgcn_mfma_f32_16x16x32_bf16(
      __builtin_bit_cast(bf16x8, a), __builtin_bit_cast(bf16x8, b), c, 0, 0, 0);
}
// 16x16x16 bf16 MFMA (K=16): A/B are 4 bf16 (2 VGPRs). Used for PV so the
// QK^T output registers feed PV directly (lane: m=l16, k=quad*4+e).
__device__ __forceinline__ f32x4 mfma16h(su4v a, su4v b, f32x4 c) {
#if __has_builtin(__builtin_amdgcn_mfma_f32_16x16x16_bf16)
  return __builtin_amdgcn_mfma_f32_16x16x16_bf16(
      __builtin_bit_cast(bf16x4, a), __builtin_bit_cast(bf16x4, b), c, 0, 0, 0);
#elif __has_builtin(__builtin_amdgcn_mfma_f32_16x16x16bf16_1k)
  return __builtin_amdgcn_mfma_f32_16x16x16bf16_1k(
      __builtin_bit_cast(s16x4, a), __builtin_bit_cast(s16x4, b), c, 0, 0, 0);
#else
  f32x4 d = c;
  asm("v_mfma_f32_16x16x16_bf16 %0, %1, %2, %0" : "+v"(d) : "v"(a), "v"(b));
  return d;
#endif
}
__device__ __forceinline__ u16 f2b(float f) {  // RNE
  unsigned int u = __builtin_bit_cast(unsigned int, f);
  u += 0x7fffu + ((u >> 16) & 1u);
  return (u16)(u >> 16);
}
__device__ __forceinline__ float b2f(u16 v) {
  unsigned int u = ((unsigned int)v) << 16;
  return __builtin_bit_cast(float, u);
}
typedef const __attribute__((address_space(1))) unsigned int* gas_t;
typedef __attribute__((address_space(3))) unsigned int* las_t;
__device__ __forceinline__ void gll16(const u16* g, u16* l) {
  __builtin_amdgcn_global_load_lds((gas_t)g, (las_t)l, 16, 0, 0);
}

// ---------------------------------------------------------------------------
// prep_weff: effective weights [out_row][in_col] bf16; Q-rows pre-scaled by QSC
// ---------------------------------------------------------------------------
__global__ __launch_bounds__(256) void prep_weff(
    const float* __restrict__ wqkv, const float* __restrict__ wproj,
    u16* __restrict__ weffQ, u16* __restrict__ weffP) {
  int tid = blockIdx.x * 256 + threadIdx.x;
  int stride = gridDim.x * 256;
  for (int i = tid; i < H3 * DIM; i += stride) {
    int row = i >> 10, col = i & 1023;
    int q = row / 768, o = row - q * 768;
    int p = col >> 8, c = col & 255;
    float v = d_SGN[q * 4 + p] * wqkv[(d_IDX[q * 4 + p] * 768 + o) * 256 + c];
    if (o < 256) v *= QSC;  // Q rows
    weffQ[i] = f2b(v);
  }
  for (int i = tid; i < DIM * DIM; i += stride) {
    int row = i >> 10, col = i & 1023;
    int q = row >> 8, o = row & 255;
    int p = col >> 8, c = col & 255;
    weffP[i] = f2b(d_SGN[q * 4 + p] * wproj[(d_IDX[q * 4 + p] * 256 + o) * 256 + c]);
  }
}

// ---------------------------------------------------------------------------
// prep_x: x (B,Cc,4,N) fp32 -> Ax bf16 [8192 (b,n)][1024 (p,c)].
// LDS transpose, layout T[n][pc] stride 264 u16 (16B-aligned su8v reads).
// ---------------------------------------------------------------------------
__global__ __launch_bounds__(256) void prep_x(
    const float* __restrict__ x, u16* __restrict__ Ax) {
  __shared__ u16 T[64 * 264];  // [n][pc], stride 264
  int blk = blockIdx.x;
  int nc = blk & 15;
  int cc = (blk >> 4) & 3;
  int b = blk >> 6;
  int n0 = nc * 64, c0 = cc * 64;
  int tid = threadIdx.x;
  int nseg = tid & 15, rq = tid >> 4;  // rq 0..15
#pragma unroll
  for (int pass = 0; pass < 16; ++pass) {
    int rr = pass * 16 + rq;  // pc local 0..255: p = rr>>6, c = rr&63
    int p = rr >> 6, c = rr & 63;
    float4 f = *(const float4*)(x + (((size_t)(b * 256 + c0 + c)) * 4 + p) * 1024 +
                                n0 + nseg * 4);
    T[(nseg * 4 + 0) * 264 + rr] = f2b(f.x);
    T[(nseg * 4 + 1) * 264 + rr] = f2b(f.y);
    T[(nseg * 4 + 2) * 264 + rr] = f2b(f.z);
    T[(nseg * 4 + 3) * 264 + rr] = f2b(f.w);
  }
  __syncthreads();
  int nl = tid >> 5, lc = tid & 31;
#pragma unroll
  for (int pass = 0; pass < 8; ++pass) {
    int n = pass * 8 + nl;
    su8v v = *(const su8v*)(&T[n * 264 + lc * 8]);
    int pcl = lc * 8;
    *(su8v*)(Ax + (size_t)(b * 1024 + n0 + n) * 1024 + (pcl >> 6) * 256 + c0 +
             (pcl & 63)) = v;
  }
}

// ---------------------------------------------------------------------------
// 8-wave GEMM core, ONE barrier per K-tile + counted vmcnt, free-running
// waves. Tile BM x BN (BM+BN == 384), BK=64, 512 threads = 8 waves of 64x64.
// 3-slot LDS ring; loads for 2 future tiles stay in flight across barriers.
// LDS rows 64 u16 = 8 x 16B blocks, XOR-swizzled (blk ^= row&7); global
// source pre-swizzled identically so gll's linear LDS write lands right.
// ---------------------------------------------------------------------------
template <int BM, int BN>
__device__ __forceinline__ void gemm_core8(
    const u16* __restrict__ Ag, const u16* __restrict__ Bg,
    u16* As, u16* Bs, int tid, f32x4 (&acc)[4][4]) {
  constexpr int WN = BN / 64;
  constexpr int AC = BM / 64;
  constexpr int BC = BN / 64;
  constexpr int NT = 16;  // K = 1024 / BK(64)
  int w = tid >> 6, lane = tid & 63, l16 = lane & 15, quad = lane >> 4;
  int wm = w / WN, wn = w % WN;
  int x7 = l16 & 7;
  int srow = lane >> 3;
  int sblk = (lane & 7) ^ srow;

  auto STAGE_A = [&](int tt, int bs) {
#pragma unroll
    for (int c = 0; c < AC; ++c) {
      int r0 = c * 64 + w * 8;
      gll16(Ag + (size_t)(r0 + srow) * 1024 + tt * 64 + sblk * 8,
            As + (size_t)bs * (BM * 64) + r0 * 64);
    }
  };
  auto STAGE_B = [&](int tt, int bs) {
#pragma unroll
    for (int c = 0; c < BC; ++c) {
      int r0 = c * 64 + w * 8;
      gll16(Bg + (size_t)(r0 + srow) * 1024 + tt * 64 + sblk * 8,
            Bs + (size_t)bs * (BN * 64) + r0 * 64);
    }
  };

  STAGE_A(0, 0); STAGE_B(0, 0);
  STAGE_A(1, 1); STAGE_B(1, 1);
  asm volatile("s_waitcnt vmcnt(6)" ::: "memory");
  __builtin_amdgcn_s_barrier();

  int cur = 0, nxt = 1, stg = 2;
  for (int t = 0; t < NT; ++t) {
    const u16* At = As + (size_t)cur * (BM * 64);
    const u16* Bt = Bs + (size_t)cur * (BN * 64);
#pragma unroll
    for (int kk = 0; kk < 2; ++kk) {
      su8v af[4], bf[4];
#pragma unroll
      for (int i = 0; i < 4; ++i)
        af[i] = *(const su8v*)(At + (wm * 64 + i * 16 + l16) * 64 +
                               ((kk * 4 + quad) ^ x7) * 8);
#pragma unroll
      for (int j = 0; j < 4; ++j)
        bf[j] = *(const su8v*)(Bt + (wn * 64 + j * 16 + l16) * 64 +
                               ((kk * 4 + quad) ^ x7) * 8);
      if (t + 2 < NT) {
        if (kk == 0) STAGE_A(t + 2, stg);
        else         STAGE_B(t + 2, stg);
      }
      __builtin_amdgcn_s_setprio(1);
#pragma unroll
      for (int i = 0; i < 4; ++i)
#pragma unroll
        for (int j = 0; j < 4; ++j)
          acc[i][j] = mfma16(af[i], bf[j], acc[i][j]);
      __builtin_amdgcn_s_setprio(0);
    }
    if (t < NT - 2)       asm volatile("s_waitcnt vmcnt(6)" ::: "memory");
    else if (t == NT - 2) asm volatile("s_waitcnt vmcnt(0)" ::: "memory");
    asm volatile("" ::: "memory");
    __builtin_amdgcn_s_barrier();
    asm volatile("" ::: "memory");
    int tmp = cur; cur = nxt; nxt = stg; stg = tmp;
  }
}

// ---------------------------------------------------------------------------
// QKV GEMM: tile = 256 (bn) x 128 (chan). Grid 32x24 = 768 blocks.
// ---------------------------------------------------------------------------
__global__ __launch_bounds__(512, 2) void gemm_qkv_mfma(
    const u16* __restrict__ Ax, const u16* __restrict__ weffQ,
    const float* __restrict__ bqkv,
    u16* __restrict__ Qb, u16* __restrict__ Kb, u16* __restrict__ VbT) {
  __shared__ u16 smem[3 * 384 * 64];  // 144 KB: 3-slot ring, A tile + B tile
  int bn0 = blockIdx.x * 256;
  int col0 = blockIdx.y * 128;
  int q = col0 / 768;
  int off = col0 - q * 768;
  int sel = off >> 8;  // 0=Q 1=K 2=V (uniform)
  int head = (q * 256 + (off & 255)) >> 7;
  int tid = threadIdx.x;
  int w = tid >> 6, lane = tid & 63, l16 = lane & 15, quad = lane >> 4;
  f32x4 acc[4][4];
#pragma unroll
  for (int i = 0; i < 4; ++i)
#pragma unroll
    for (int j = 0; j < 4; ++j) acc[i][j] = (f32x4){0.f, 0.f, 0.f, 0.f};

  if (sel == 2) {
    // ---- V: m=bn (256), n=chan (128) ----
    gemm_core8<256, 128>(Ax + (size_t)bn0 * 1024, weffQ + (size_t)col0 * 1024,
                         smem, smem + 3 * 256 * 64, tid, acc);
    int wm = w >> 1, wn = w & 1;
#pragma unroll
    for (int j = 0; j < 4; ++j) {
      int dl = wn * 64 + j * 16 + l16;
      float bias = bqkv[col0 + dl];
#pragma unroll
      for (int i = 0; i < 4; ++i) {
        int m = bn0 + wm * 64 + i * 16 + quad * 4;
        int b = m >> 10, npos = m & 1023;
        int bh = b * NHD + head;
        su4v pk;
#pragma unroll
        for (int r = 0; r < 4; ++r) pk[r] = f2b(acc[i][j][r] + bias);
        *(su4v*)(VbT + ((size_t)bh * DD + dl) * NN + npos) = pk;
      }
    }
  } else {
    // ---- Q/K: m=chan (128), n=bn (256) ----
    gemm_core8<128, 256>(weffQ + (size_t)col0 * 1024, Ax + (size_t)bn0 * 1024,
                         smem, smem + 3 * 128 * 64, tid, acc);
    int wm = w >> 2, wn = w & 3;
    u16* dst = (sel == 0) ? Qb : Kb;
    float sc = (sel == 0) ? (float)QSC : 1.0f;
#pragma unroll
    for (int i = 0; i < 4; ++i) {
      int dbase = wm * 64 + i * 16 + quad * 4;
      float4 b4 = *(const float4*)(bqkv + col0 + dbase);
#pragma unroll
      for (int j = 0; j < 4; ++j) {
        int n = bn0 + wn * 64 + j * 16 + l16;
        int b = n >> 10, npos = n & 1023;
        int bh = b * NHD + head;
        su4v pk;
        pk[0] = f2b(acc[i][j][0] + b4.x * sc);
        pk[1] = f2b(acc[i][j][1] + b4.y * sc);
        pk[2] = f2b(acc[i][j][2] + b4.z * sc);
        pk[3] = f2b(acc[i][j][3] + b4.w * sc);
        *(su4v*)(dst + ((size_t)bh * NN + npos) * DD + dbase) = pk;
      }
    }
  }
}

// ---------------------------------------------------------------------------
// Flash attention, split-K x2: 1024 blocks = half(2) x qt(8) x bh(64).
// 128 q x 512 keys per block. Single-buffered K/V (32 KB -> full residency,
// 4 blocks/CU). NO P LDS round-trip: QK^T computes S^T (lane: q=l16,
// key=j*16+quad*4+r), which IS the A-fragment layout of 16x16x16 MFMA
// (m=l16, k=quad*4+e). P stays in registers as packed bf16x4 and feeds PV
// directly; V B-fragment (n=d=l16, k=quad*4+e) is a swizzled ds_read_b64
// from Vt. Removes 8 ds_write_b64 + 4 ds_read_b128 per wave per kt and the
// associated bank conflicts (round-2: 3.67M cycles, all from the P scatter).
// ---------------------------------------------------------------------------
__global__ __launch_bounds__(256, 4) void attn_mfma(
    const u16* __restrict__ Qb, const u16* __restrict__ Kb,
    const u16* __restrict__ VbT, u16* __restrict__ OP,
    float* __restrict__ LS) {
  __shared__ u16 Ks[64 * 128];  // 16 KB, xor-swizzled 16B blocks
  __shared__ u16 Vt[128 * 64];  // 16 KB, xor-swizzled 16B blocks
  int blk = blockIdx.x;
  int bh = blk & 63;  // low bits -> blk%8 == bh%8 (same XCD for K/V L2 reuse)
  int rest = blk >> 6;
  int qt = rest & 7;
  int half = rest >> 3;
  int n0 = qt * 128;
  int tid = threadIdx.x;
  int w = tid >> 6, lane = tid & 63, l16 = lane & 15, quad = lane >> 4;
  const u16* Qg = Qb + ((size_t)bh * NN + n0) * DD;
  const u16* Kg = Kb + (size_t)bh * NN * DD;
  const u16* Vg = VbT + (size_t)bh * DD * NN;
  int x7 = l16 & 7;

  su8v qreg[2][4];  // B-fragment: n=q (l16), k=d
#pragma unroll
  for (int mi = 0; mi < 2; ++mi)
#pragma unroll
    for (int ch = 0; ch < 4; ++ch)
      qreg[mi][ch] = *(const su8v*)(Qg + (size_t)(w * 32 + mi * 16 + l16) * DD +
                                    ch * 32 + quad * 8);

  float ls[2] = {0.f, 0.f};
  f32x4 accO[2][8];
#pragma unroll
  for (int mi = 0; mi < 2; ++mi)
#pragma unroll
    for (int dt = 0; dt < 8; ++dt) accO[mi][dt] = (f32x4){0.f, 0.f, 0.f, 0.f};

  for (int kt = 0; kt < 8; ++kt) {
    int c0 = half * 512 + kt * 64;
    __syncthreads();
#pragma unroll
    for (int t = 0; t < 4; ++t) {
      int ci = w * 4 + t;
      // K: rows of 256B = 16 x 16B blocks; block low-3-bits xor row&7
      int krow = ci * 4 + (lane >> 4);
      int kblk = (lane & 15) ^ (krow & 7);
      gll16(Kg + (size_t)(c0 + krow) * DD + kblk * 8, Ks + ci * 512);
      // V^T: rows of 128B = 8 x 16B blocks; xor-swizzled
      int dv = ci * 8 + (lane >> 3);
      int vblk = (lane & 7) ^ (dv & 7);
      gll16(Vg + (size_t)dv * NN + c0 + vblk * 8, Vt + ci * 512);
    }
    __syncthreads();

    // QK^T per 16-key slice j, immediately exp2 into packed registers.
    su4v pk[2][4];
#pragma unroll
    for (int j = 0; j < 4; ++j) {
      f32x4 s0 = (f32x4){0.f, 0.f, 0.f, 0.f};
      f32x4 s1 = (f32x4){0.f, 0.f, 0.f, 0.f};
#pragma unroll
      for (int ch = 0; ch < 4; ++ch) {
        su8v kf = *(const su8v*)(Ks + (j * 16 + l16) * 128 +
                                 (((ch * 4 + quad) ^ x7) * 8));
        s0 = mfma16(kf, qreg[0][ch], s0);
        s1 = mfma16(kf, qreg[1][ch], s1);
      }
      su4v p0, p1;
#pragma unroll
      for (int r = 0; r < 4; ++r) {
        float pa = __builtin_exp2f(s0[r]);
        ls[0] += pa;
        p0[r] = (u16)(__builtin_bit_cast(unsigned int, pa) >> 16);
        float pb = __builtin_exp2f(s1[r]);
        ls[1] += pb;
        p1[r] = (u16)(__builtin_bit_cast(unsigned int, pb) >> 16);
      }
      pk[0][j] = p0;
      pk[1][j] = p1;
    }

    // O += P V : P direct from registers (A-frag), V via b64 (B-frag).
#pragma unroll
    for (int j = 0; j < 4; ++j) {
#pragma unroll
      for (int dt = 0; dt < 8; ++dt) {
        su4v vf = *(const su4v*)(Vt + (dt * 16 + l16) * 64 +
                                 ((((j * 2 + (quad >> 1)) ^ x7) << 3) +
                                  (quad & 1) * 4));
        accO[0][dt] = mfma16h(pk[0][j], vf, accO[0][dt]);
        accO[1][dt] = mfma16h(pk[1][j], vf, accO[1][dt]);
      }
    }
  }

  // row-sum: reduce over quad lanes (bits 4,5) -> all lanes hold full sum
#pragma unroll
  for (int mi = 0; mi < 2; ++mi) {
    float s = ls[mi];
    s += __shfl_xor(s, 16, 64);
    s += __shfl_xor(s, 32, 64);
    ls[mi] = s;
  }
  size_t hb = (size_t)(half * 64 + bh);
  if (quad == 0) {
#pragma unroll
    for (int mi = 0; mi < 2; ++mi)
      LS[hb * NN + n0 + w * 32 + mi * 16 + l16] = ls[mi];
  }
  // store unnormalized O partial (bf16)
#pragma unroll
  for (int mi = 0; mi < 2; ++mi)
#pragma unroll
    for (int r = 0; r < 4; ++r) {
      int row = w * 32 + mi * 16 + quad * 4 + r;
      size_t base = (hb * NN + n0 + row) * DD;
#pragma unroll
      for (int dt = 0; dt < 8; ++dt)
        OP[base + dt * 16 + l16] = f2b(accO[mi][dt][r]);
    }
}

// ---------------------------------------------------------------------------
// merge: AO[b,n][head*128+d] = (O0 + O1) / (l0 + l1)
// ---------------------------------------------------------------------------
__global__ __launch_bounds__(256) void attn_merge(
    const u16* __restrict__ OP, const float* __restrict__ LS,
    u16* __restrict__ AO) {
  size_t idx = (size_t)blockIdx.x * 256 + threadIdx.x;  // 4-elem chunk id
  size_t e = idx * 4;
  int d = (int)(e & 127);
  size_t bhn = e >> 7;  // bh*1024 + n
  su4v a = *(const su4v*)(OP + bhn * DD + d);
  su4v b = *(const su4v*)(OP + (size_t)64 * NN * DD + bhn * DD + d);
  float inv = 1.0f / (LS[bhn] + LS[bhn + 64 * NN]);
  int bh = (int)(bhn >> 10), n = (int)(bhn & 1023);
  int bb = bh >> 3, head = bh & 7;
  su4v o;
#pragma unroll
  for (int r = 0; r < 4; ++r) o[r] = f2b((b2f(a[r]) + b2f(b[r])) * inv);
  *(su4v*)(AO + ((size_t)(bb * 1024 + n) * 1024) + head * 128 + d) = o;
}

// ---------------------------------------------------------------------------
// quaternion depthwise 3x3 conv (fp32) — writes PE term into workspace
// ---------------------------------------------------------------------------
__global__ __launch_bounds__(256) void qdwconv_kernel(
    const float* __restrict__ x, const float* __restrict__ wpe,
    const float* __restrict__ bpe, float* __restrict__ pe) {
  int blk = blockIdx.x;
  int co = blk & 255;
  int b = blk >> 8;
  __shared__ float pl[4][34 * 34];
  __shared__ float wsm[4][9];
  int tid = threadIdx.x;
  for (int i = tid; i < 4 * 34 * 34; i += 256) ((float*)pl)[i] = 0.f;
  if (tid < 36) wsm[tid / 9][tid % 9] = wpe[((tid / 9) * 256 + co) * 9 + tid % 9];
  __syncthreads();
  for (int i = tid; i < 4 * 1024; i += 256) {
    int p = i >> 10, n = i & 1023;
    int h = n >> 5, ww = n & 31;
    pl[p][(h + 1) * 34 + (ww + 1)] =
        x[(((size_t)b * 256 + co) * 4 + p) * 1024 + n];
  }
  __syncthreads();
  for (int n = tid; n < 1024; n += 256) {
    int h = n >> 5, ww = n & 31;
    float in[4][9];
#pragma unroll
    for (int p = 0; p < 4; ++p)
#pragma unroll
      for (int t = 0; t < 9; ++t)
        in[p][t] = pl[p][(h + t / 3) * 34 + (ww + t % 3)];
#pragma unroll
    for (int q = 0; q < 4; ++q) {
      float acc = bpe[q * 256 + co];
#pragma unroll
      for (int p = 0; p < 4; ++p) {
        int idx = d_IDX[q * 4 + p];
        float s = d_SGN[q * 4 + p];
        float sub = 0.f;
#pragma unroll
        for (int t = 0; t < 9; ++t) sub += in[p][t] * wsm[idx][t];
        acc += s * sub;
      }
      pe[(((size_t)b * 256 + co) * 4 + q) * 1024 + n] = acc;
    }
  }
}

// ---------------------------------------------------------------------------
// proj GEMM: tile = 256 (bn) x 128 (q,o). Grid 32x8 = 256 blocks.
// ---------------------------------------------------------------------------
__global__ __launch_bounds__(512, 2) void gemm_proj_mfma(
    const u16* __restrict__ AO, const u16* __restrict__ weffP,
    const float* __restrict__ bproj, const float* __restrict__ pe,
    float* __restrict__ out) {
  __shared__ u16 smem[3 * 384 * 64];  // 144 KB ring
  int n0 = blockIdx.x * 256;
  int m0 = blockIdx.y * 128;
  int tid = threadIdx.x;
  f32x4 acc[4][4];
#pragma unroll
  for (int i = 0; i < 4; ++i)
#pragma unroll
    for (int j = 0; j < 4; ++j) acc[i][j] = (f32x4){0.f, 0.f, 0.f, 0.f};
  gemm_core8<128, 256>(weffP + (size_t)m0 * 1024, AO + (size_t)n0 * 1024,
                       smem, smem + 3 * 128 * 64, tid, acc);

  int w = tid >> 6, lane = tid & 63, l16 = lane & 15, quad = lane >> 4;
  int wm = w >> 2, wn = w & 3;
#pragma unroll
  for (int i = 0; i < 4; ++i) {
#pragma unroll
    for (int r = 0; r < 4; ++r) {
      int mrow = m0 + wm * 64 + i * 16 + quad * 4 + r;
      int q = mrow >> 8, o = mrow & 255;
      float bias = bproj[mrow];
#pragma unroll
      for (int j = 0; j < 4; ++j) {
        int n = n0 + wn * 64 + j * 16 + l16;
        int b = n >> 10, npos = n & 1023;
        size_t oidx = (((size_t)b * 256 + o) * 4 + q) * 1024 + npos;
        out[oidx] = pe[oidx] + acc[i][j][r] + bias;
      }
    }
  }
}

// ---------------------------------------------------------------------------
extern "C" void kernel_launch(void* const* d_in, const int* in_sizes, int n_in,
                              void* d_out, int out_size, void* d_ws,
                              size_t ws_size, hipStream_t stream) {
  const float* x      = (const float*)d_in[0];
  const float* w_qkv  = (const float*)d_in[1];
  const float* b_qkv  = (const float*)d_in[2];
  const float* w_proj = (const float*)d_in[3];
  const float* b_proj = (const float*)d_in[4];
  const float* w_pe   = (const float*)d_in[5];
  const float* b_pe   = (const float*)d_in[6];
  float* out = (float*)d_out;

  u16* ws = (u16*)d_ws;
  u16* weffQ = ws;                                   // 3072*1024
  u16* weffP = weffQ + (size_t)H3 * DIM;             // 1024*1024
  u16* Ax    = weffP + (size_t)DIM * DIM;            // 8192*1024
  u16* Qb    = Ax + (size_t)MM * DIM;                // 64*1024*128
  u16* Kb    = Qb + (size_t)BB * NHD * NN * DD;      // 64*1024*128
  u16* VbT   = Kb + (size_t)BB * NHD * NN * DD;      // 64*128*1024
  u16* AO    = VbT + (size_t)BB * NHD * DD * NN;     // 8192*1024
  float* PE  = (float*)(AO + (size_t)MM * DIM);      // 8192*1024 fp32
  u16* OP    = (u16*)(PE + (size_t)MM * DIM);        // 2*64*1024*128 bf16
  float* LS  = (float*)(OP + (size_t)2 * 64 * NN * DD);  // 2*64*1024 fp32
  // total ~160 MB scratch

  hipLaunchKernelGGL(prep_weff, dim3(4096), dim3(256), 0, stream,
                     w_qkv, w_proj, weffQ, weffP);
  hipLaunchKernelGGL(prep_x, dim3(512), dim3(256), 0, stream, x, Ax);
  hipLaunchKernelGGL(gemm_qkv_mfma, dim3(MM / 256, H3 / 128), dim3(512), 0,
                     stream, Ax, weffQ, b_qkv, Qb, Kb, VbT);
  hipLaunchKernelGGL(attn_mfma, dim3(1024), dim3(256), 0, stream,
                     Qb, Kb, VbT, OP, LS);
  hipLaunchKernelGGL(attn_merge, dim3((64 * NN * DD) / (256 * 4)), dim3(256),
                     0, stream, OP, LS, AO);
  hipLaunchKernelGGL(qdwconv_kernel, dim3(BB * 256), dim3(256), 0, stream,
                     x, w_pe, b_pe, PE);
  hipLaunchKernelGGL(gemm_proj_mfma, dim3(MM / 256, DIM / 128), dim3(512), 0,
                     stream, AO, weffP, b_proj, PE, out);
}

// Round 7
// 339.168 us; speedup vs baseline: 1.0670x; 1.0670x over previous
//
#include <hip/hip_runtime.h>
#include <hip/hip_bf16.h>

typedef unsigned short u16;
typedef float f32x4 __attribute__((ext_vector_type(4)));
typedef __bf16 bf16x8 __attribute__((ext_vector_type(8)));
typedef __bf16 bf16x4 __attribute__((ext_vector_type(4)));
typedef unsigned short su8v __attribute__((ext_vector_type(8)));
typedef unsigned short su4v __attribute__((ext_vector_type(4)));
typedef short s16x4 __attribute__((ext_vector_type(4)));

#define BB 8
#define NHD 8
#define DD 128
#define NN 1024
#define DIM 1024
#define H3 3072
#define MM 8192
// scale * log2(e), folded into Q weights so softmax is exp2(raw dot)
#define QSC (0.08838834764831845f * 1.4426950408889634f)

__constant__ int   d_IDX[16] = {0,1,2,3, 1,0,3,2, 2,3,0,1, 3,2,1,0};
__constant__ float d_SGN[16] = {1.f,-1.f,-1.f,-1.f, 1.f,1.f,1.f,-1.f,
                                1.f,-1.f,1.f,1.f,  1.f,1.f,-1.f,1.f};

__device__ __forceinline__ f32x4 mfma16(su8v a, su8v b, f32x4 c) {
  return __builtin_amdgcn_mfma_f32_16x16x32_bf16(
      __builtin_bit_cast(bf16x8, a), __builtin_bit_cast(bf16x8, b), c, 0, 0, 0);
}
// 16x16x16 bf16 MFMA (K=16): A/B are 4 bf16 (2 VGPRs). Used for PV so the
// QK^T output registers feed PV directly (lane: m=l16, k=quad*4+e).
__device__ __forceinline__ f32x4 mfma16h(su4v a, su4v b, f32x4 c) {
#if __has_builtin(__builtin_amdgcn_mfma_f32_16x16x16_bf16)
  return __builtin_amdgcn_mfma_f32_16x16x16_bf16(
      __builtin_bit_cast(bf16x4, a), __builtin_bit_cast(bf16x4, b), c, 0, 0, 0);
#elif __has_builtin(__builtin_amdgcn_mfma_f32_16x16x16bf16_1k)
  return __builtin_amdgcn_mfma_f32_16x16x16bf16_1k(
      __builtin_bit_cast(s16x4, a), __builtin_bit_cast(s16x4, b), c, 0, 0, 0);
#else
  f32x4 d = c;
  asm("v_mfma_f32_16x16x16_bf16 %0, %1, %2, %0" : "+v"(d) : "v"(a), "v"(b));
  return d;
#endif
}
__device__ __forceinline__ u16 f2b(float f) {  // RNE
  unsigned int u = __builtin_bit_cast(unsigned int, f);
  u += 0x7fffu + ((u >> 16) & 1u);
  return (u16)(u >> 16);
}
__device__ __forceinline__ float b2f(u16 v) {
  unsigned int u = ((unsigned int)v) << 16;
  return __builtin_bit_cast(float, u);
}
typedef const __attribute__((address_space(1))) unsigned int* gas_t;
typedef __attribute__((address_space(3))) unsigned int* las_t;
__device__ __forceinline__ void gll16(const u16* g, u16* l) {
  __builtin_amdgcn_global_load_lds((gas_t)g, (las_t)l, 16, 0, 0);
}

// ---------------------------------------------------------------------------
// prep_weff: effective weights [out_row][in_col] bf16; Q-rows pre-scaled by QSC
// ---------------------------------------------------------------------------
__global__ __launch_bounds__(256) void prep_weff(
    const float* __restrict__ wqkv, const float* __restrict__ wproj,
    u16* __restrict__ weffQ, u16* __restrict__ weffP) {
  int tid = blockIdx.x * 256 + threadIdx.x;
  int stride = gridDim.x * 256;
  for (int i = tid; i < H3 * DIM; i += stride) {
    int row = i >> 10, col = i & 1023;
    int q = row / 768, o = row - q * 768;
    int p = col >> 8, c = col & 255;
    float v = d_SGN[q * 4 + p] * wqkv[(d_IDX[q * 4 + p] * 768 + o) * 256 + c];
    if (o < 256) v *= QSC;  // Q rows
    weffQ[i] = f2b(v);
  }
  for (int i = tid; i < DIM * DIM; i += stride) {
    int row = i >> 10, col = i & 1023;
    int q = row >> 8, o = row & 255;
    int p = col >> 8, c = col & 255;
    weffP[i] = f2b(d_SGN[q * 4 + p] * wproj[(d_IDX[q * 4 + p] * 256 + o) * 256 + c]);
  }
}

// ---------------------------------------------------------------------------
// prep_x: x (B,Cc,4,N) fp32 -> Ax bf16 [8192 (b,n)][1024 (p,c)].
// LDS transpose, layout T[n][pc] stride 264 u16 (16B-aligned su8v reads).
// ---------------------------------------------------------------------------
__global__ __launch_bounds__(256) void prep_x(
    const float* __restrict__ x, u16* __restrict__ Ax) {
  __shared__ u16 T[64 * 264];  // [n][pc], stride 264
  int blk = blockIdx.x;
  int nc = blk & 15;
  int cc = (blk >> 4) & 3;
  int b = blk >> 6;
  int n0 = nc * 64, c0 = cc * 64;
  int tid = threadIdx.x;
  int nseg = tid & 15, rq = tid >> 4;  // rq 0..15
#pragma unroll
  for (int pass = 0; pass < 16; ++pass) {
    int rr = pass * 16 + rq;  // pc local 0..255: p = rr>>6, c = rr&63
    int p = rr >> 6, c = rr & 63;
    float4 f = *(const float4*)(x + (((size_t)(b * 256 + c0 + c)) * 4 + p) * 1024 +
                                n0 + nseg * 4);
    T[(nseg * 4 + 0) * 264 + rr] = f2b(f.x);
    T[(nseg * 4 + 1) * 264 + rr] = f2b(f.y);
    T[(nseg * 4 + 2) * 264 + rr] = f2b(f.z);
    T[(nseg * 4 + 3) * 264 + rr] = f2b(f.w);
  }
  __syncthreads();
  int nl = tid >> 5, lc = tid & 31;
#pragma unroll
  for (int pass = 0; pass < 8; ++pass) {
    int n = pass * 8 + nl;
    su8v v = *(const su8v*)(&T[n * 264 + lc * 8]);
    int pcl = lc * 8;
    *(su8v*)(Ax + (size_t)(b * 1024 + n0 + n) * 1024 + (pcl >> 6) * 256 + c0 +
             (pcl & 63)) = v;
  }
}

// ---------------------------------------------------------------------------
// 8-wave GEMM core, ONE barrier per K-tile + counted vmcnt, free-running
// waves. Tile BM x BN (BM+BN == 384), BK=64, 512 threads = 8 waves of 64x64.
// 3-slot LDS ring; loads for 2 future tiles stay in flight across barriers.
// LDS rows 64 u16 = 8 x 16B blocks, XOR-swizzled (blk ^= row&7); global
// source pre-swizzled identically so gll's linear LDS write lands right.
// ---------------------------------------------------------------------------
template <int BM, int BN>
__device__ __forceinline__ void gemm_core8(
    const u16* __restrict__ Ag, const u16* __restrict__ Bg,
    u16* As, u16* Bs, int tid, f32x4 (&acc)[4][4]) {
  constexpr int WN = BN / 64;
  constexpr int AC = BM / 64;
  constexpr int BC = BN / 64;
  constexpr int NT = 16;  // K = 1024 / BK(64)
  int w = tid >> 6, lane = tid & 63, l16 = lane & 15, quad = lane >> 4;
  int wm = w / WN, wn = w % WN;
  int x7 = l16 & 7;
  int srow = lane >> 3;
  int sblk = (lane & 7) ^ srow;

  auto STAGE_A = [&](int tt, int bs) {
#pragma unroll
    for (int c = 0; c < AC; ++c) {
      int r0 = c * 64 + w * 8;
      gll16(Ag + (size_t)(r0 + srow) * 1024 + tt * 64 + sblk * 8,
            As + (size_t)bs * (BM * 64) + r0 * 64);
    }
  };
  auto STAGE_B = [&](int tt, int bs) {
#pragma unroll
    for (int c = 0; c < BC; ++c) {
      int r0 = c * 64 + w * 8;
      gll16(Bg + (size_t)(r0 + srow) * 1024 + tt * 64 + sblk * 8,
            Bs + (size_t)bs * (BN * 64) + r0 * 64);
    }
  };

  STAGE_A(0, 0); STAGE_B(0, 0);
  STAGE_A(1, 1); STAGE_B(1, 1);
  asm volatile("s_waitcnt vmcnt(6)" ::: "memory");
  __builtin_amdgcn_s_barrier();

  int cur = 0, nxt = 1, stg = 2;
  for (int t = 0; t < NT; ++t) {
    const u16* At = As + (size_t)cur * (BM * 64);
    const u16* Bt = Bs + (size_t)cur * (BN * 64);
#pragma unroll
    for (int kk = 0; kk < 2; ++kk) {
      su8v af[4], bf[4];
#pragma unroll
      for (int i = 0; i < 4; ++i)
        af[i] = *(const su8v*)(At + (wm * 64 + i * 16 + l16) * 64 +
                               ((kk * 4 + quad) ^ x7) * 8);
#pragma unroll
      for (int j = 0; j < 4; ++j)
        bf[j] = *(const su8v*)(Bt + (wn * 64 + j * 16 + l16) * 64 +
                               ((kk * 4 + quad) ^ x7) * 8);
      if (t + 2 < NT) {
        if (kk == 0) STAGE_A(t + 2, stg);
        else         STAGE_B(t + 2, stg);
      }
      __builtin_amdgcn_s_setprio(1);
#pragma unroll
      for (int i = 0; i < 4; ++i)
#pragma unroll
        for (int j = 0; j < 4; ++j)
          acc[i][j] = mfma16(af[i], bf[j], acc[i][j]);
      __builtin_amdgcn_s_setprio(0);
    }
    if (t < NT - 2)       asm volatile("s_waitcnt vmcnt(6)" ::: "memory");
    else if (t == NT - 2) asm volatile("s_waitcnt vmcnt(0)" ::: "memory");
    asm volatile("" ::: "memory");
    __builtin_amdgcn_s_barrier();
    asm volatile("" ::: "memory");
    int tmp = cur; cur = nxt; nxt = stg; stg = tmp;
  }
}

// ---------------------------------------------------------------------------
// QKV GEMM: tile = 256 (bn) x 128 (chan). Grid 32x24 = 768 blocks.
// ---------------------------------------------------------------------------
__global__ __launch_bounds__(512, 2) void gemm_qkv_mfma(
    const u16* __restrict__ Ax, const u16* __restrict__ weffQ,
    const float* __restrict__ bqkv,
    u16* __restrict__ Qb, u16* __restrict__ Kb, u16* __restrict__ VbT) {
  __shared__ u16 smem[3 * 384 * 64];  // 144 KB: 3-slot ring, A tile + B tile
  int bn0 = blockIdx.x * 256;
  int col0 = blockIdx.y * 128;
  int q = col0 / 768;
  int off = col0 - q * 768;
  int sel = off >> 8;  // 0=Q 1=K 2=V (uniform)
  int head = (q * 256 + (off & 255)) >> 7;
  int tid = threadIdx.x;
  int w = tid >> 6, lane = tid & 63, l16 = lane & 15, quad = lane >> 4;
  f32x4 acc[4][4];
#pragma unroll
  for (int i = 0; i < 4; ++i)
#pragma unroll
    for (int j = 0; j < 4; ++j) acc[i][j] = (f32x4){0.f, 0.f, 0.f, 0.f};

  if (sel == 2) {
    // ---- V: m=bn (256), n=chan (128) ----
    gemm_core8<256, 128>(Ax + (size_t)bn0 * 1024, weffQ + (size_t)col0 * 1024,
                         smem, smem + 3 * 256 * 64, tid, acc);
    int wm = w >> 1, wn = w & 1;
#pragma unroll
    for (int j = 0; j < 4; ++j) {
      int dl = wn * 64 + j * 16 + l16;
      float bias = bqkv[col0 + dl];
#pragma unroll
      for (int i = 0; i < 4; ++i) {
        int m = bn0 + wm * 64 + i * 16 + quad * 4;
        int b = m >> 10, npos = m & 1023;
        int bh = b * NHD + head;
        su4v pk;
#pragma unroll
        for (int r = 0; r < 4; ++r) pk[r] = f2b(acc[i][j][r] + bias);
        *(su4v*)(VbT + ((size_t)bh * DD + dl) * NN + npos) = pk;
      }
    }
  } else {
    // ---- Q/K: m=chan (128), n=bn (256) ----
    gemm_core8<128, 256>(weffQ + (size_t)col0 * 1024, Ax + (size_t)bn0 * 1024,
                         smem, smem + 3 * 128 * 64, tid, acc);
    int wm = w >> 2, wn = w & 3;
    u16* dst = (sel == 0) ? Qb : Kb;
    float sc = (sel == 0) ? (float)QSC : 1.0f;
#pragma unroll
    for (int i = 0; i < 4; ++i) {
      int dbase = wm * 64 + i * 16 + quad * 4;
      float4 b4 = *(const float4*)(bqkv + col0 + dbase);
#pragma unroll
      for (int j = 0; j < 4; ++j) {
        int n = bn0 + wn * 64 + j * 16 + l16;
        int b = n >> 10, npos = n & 1023;
        int bh = b * NHD + head;
        su4v pk;
        pk[0] = f2b(acc[i][j][0] + b4.x * sc);
        pk[1] = f2b(acc[i][j][1] + b4.y * sc);
        pk[2] = f2b(acc[i][j][2] + b4.z * sc);
        pk[3] = f2b(acc[i][j][3] + b4.w * sc);
        *(su4v*)(dst + ((size_t)bh * NN + npos) * DD + dbase) = pk;
      }
    }
  }
}

// ---------------------------------------------------------------------------
// Flash attention, split-K x2: 1024 blocks = half(2) x qt(8) x bh(64).
// 128 q x 512 keys per block. Single-buffered K/V (32 KB). In-register P:
// QK^T computes S^T per 16-key slice j (lane: q=l16, key=j*16+quad*4+r),
// which IS the A-fragment of 16x16x16 MFMA; exp2+pack feeds PV directly.
// j-loop FUSED (QK slice -> exp2 -> PV slice) so pk recycles per slice:
// live regs ~ qreg(32)+accO(64)+pk(8)+temps, target <=170.
// __launch_bounds__(256,3): VGPR cap ~170 -> NO SPILL (round-6's (256,4)
// forced cap 128 -> alloc collapse + 160MB scratch spill traffic).
// ---------------------------------------------------------------------------
__global__ __launch_bounds__(256, 3) void attn_mfma(
    const u16* __restrict__ Qb, const u16* __restrict__ Kb,
    const u16* __restrict__ VbT, u16* __restrict__ OP,
    float* __restrict__ LS) {
  __shared__ u16 Ks[64 * 128];  // 16 KB, xor-swizzled 16B blocks
  __shared__ u16 Vt[128 * 64];  // 16 KB, xor-swizzled 16B blocks
  int blk = blockIdx.x;
  int bh = blk & 63;  // low bits -> blk%8 == bh%8 (same XCD for K/V L2 reuse)
  int rest = blk >> 6;
  int qt = rest & 7;
  int half = rest >> 3;
  int n0 = qt * 128;
  int tid = threadIdx.x;
  int w = tid >> 6, lane = tid & 63, l16 = lane & 15, quad = lane >> 4;
  const u16* Qg = Qb + ((size_t)bh * NN + n0) * DD;
  const u16* Kg = Kb + (size_t)bh * NN * DD;
  const u16* Vg = VbT + (size_t)bh * DD * NN;
  int x7 = l16 & 7;

  su8v qreg[2][4];  // B-fragment: n=q (l16), k=d
#pragma unroll
  for (int mi = 0; mi < 2; ++mi)
#pragma unroll
    for (int ch = 0; ch < 4; ++ch)
      qreg[mi][ch] = *(const su8v*)(Qg + (size_t)(w * 32 + mi * 16 + l16) * DD +
                                    ch * 32 + quad * 8);

  float ls[2] = {0.f, 0.f};
  f32x4 accO[2][8];
#pragma unroll
  for (int mi = 0; mi < 2; ++mi)
#pragma unroll
    for (int dt = 0; dt < 8; ++dt) accO[mi][dt] = (f32x4){0.f, 0.f, 0.f, 0.f};

  for (int kt = 0; kt < 8; ++kt) {
    int c0 = half * 512 + kt * 64;
    __syncthreads();
#pragma unroll
    for (int t = 0; t < 4; ++t) {
      int ci = w * 4 + t;
      // K: rows of 256B = 16 x 16B blocks; block low-3-bits xor row&7
      int krow = ci * 4 + (lane >> 4);
      int kblk = (lane & 15) ^ (krow & 7);
      gll16(Kg + (size_t)(c0 + krow) * DD + kblk * 8, Ks + ci * 512);
      // V^T: rows of 128B = 8 x 16B blocks; xor-swizzled
      int dv = ci * 8 + (lane >> 3);
      int vblk = (lane & 7) ^ (dv & 7);
      gll16(Vg + (size_t)dv * NN + c0 + vblk * 8, Vt + ci * 512);
    }
    __syncthreads();

    // fused per-16-key-slice: QK^T -> exp2/pack -> PV (pk recycles per j)
#pragma unroll
    for (int j = 0; j < 4; ++j) {
      f32x4 s0 = (f32x4){0.f, 0.f, 0.f, 0.f};
      f32x4 s1 = (f32x4){0.f, 0.f, 0.f, 0.f};
#pragma unroll
      for (int ch = 0; ch < 4; ++ch) {
        su8v kf = *(const su8v*)(Ks + (j * 16 + l16) * 128 +
                                 (((ch * 4 + quad) ^ x7) * 8));
        s0 = mfma16(kf, qreg[0][ch], s0);
        s1 = mfma16(kf, qreg[1][ch], s1);
      }
      su4v p0, p1;
#pragma unroll
      for (int r = 0; r < 4; ++r) {
        float pa = __builtin_exp2f(s0[r]);
        ls[0] += pa;
        p0[r] = (u16)(__builtin_bit_cast(unsigned int, pa) >> 16);
        float pb = __builtin_exp2f(s1[r]);
        ls[1] += pb;
        p1[r] = (u16)(__builtin_bit_cast(unsigned int, pb) >> 16);
      }
#pragma unroll
      for (int dt = 0; dt < 8; ++dt) {
        su4v vf = *(const su4v*)(Vt + (dt * 16 + l16) * 64 +
                                 ((((j * 2 + (quad >> 1)) ^ x7) << 3) +
                                  (quad & 1) * 4));
        accO[0][dt] = mfma16h(p0, vf, accO[0][dt]);
        accO[1][dt] = mfma16h(p1, vf, accO[1][dt]);
      }
    }
  }

  // row-sum: reduce over quad lanes (bits 4,5) -> all lanes hold full sum
#pragma unroll
  for (int mi = 0; mi < 2; ++mi) {
    float s = ls[mi];
    s += __shfl_xor(s, 16, 64);
    s += __shfl_xor(s, 32, 64);
    ls[mi] = s;
  }
  size_t hb = (size_t)(half * 64 + bh);
  if (quad == 0) {
#pragma unroll
    for (int mi = 0; mi < 2; ++mi)
      LS[hb * NN + n0 + w * 32 + mi * 16 + l16] = ls[mi];
  }
  // store unnormalized O partial (bf16)
#pragma unroll
  for (int mi = 0; mi < 2; ++mi)
#pragma unroll
    for (int r = 0; r < 4; ++r) {
      int row = w * 32 + mi * 16 + quad * 4 + r;
      size_t base = (hb * NN + n0 + row) * DD;
#pragma unroll
      for (int dt = 0; dt < 8; ++dt)
        OP[base + dt * 16 + l16] = f2b(accO[mi][dt][r]);
    }
}

// ---------------------------------------------------------------------------
// merge: AO[b,n][head*128+d] = (O0 + O1) / (l0 + l1)
// ---------------------------------------------------------------------------
__global__ __launch_bounds__(256) void attn_merge(
    const u16* __restrict__ OP, const float* __restrict__ LS,
    u16* __restrict__ AO) {
  size_t idx = (size_t)blockIdx.x * 256 + threadIdx.x;  // 4-elem chunk id
  size_t e = idx * 4;
  int d = (int)(e & 127);
  size_t bhn = e >> 7;  // bh*1024 + n
  su4v a = *(const su4v*)(OP + bhn * DD + d);
  su4v b = *(const su4v*)(OP + (size_t)64 * NN * DD + bhn * DD + d);
  float inv = 1.0f / (LS[bhn] + LS[bhn + 64 * NN]);
  int bh = (int)(bhn >> 10), n = (int)(bhn & 1023);
  int bb = bh >> 3, head = bh & 7;
  su4v o;
#pragma unroll
  for (int r = 0; r < 4; ++r) o[r] = f2b((b2f(a[r]) + b2f(b[r])) * inv);
  *(su4v*)(AO + ((size_t)(bb * 1024 + n) * 1024) + head * 128 + d) = o;
}

// ---------------------------------------------------------------------------
// quaternion depthwise 3x3 conv (fp32) — writes PE term into workspace
// ---------------------------------------------------------------------------
__global__ __launch_bounds__(256) void qdwconv_kernel(
    const float* __restrict__ x, const float* __restrict__ wpe,
    const float* __restrict__ bpe, float* __restrict__ pe) {
  int blk = blockIdx.x;
  int co = blk & 255;
  int b = blk >> 8;
  __shared__ float pl[4][34 * 34];
  __shared__ float wsm[4][9];
  int tid = threadIdx.x;
  for (int i = tid; i < 4 * 34 * 34; i += 256) ((float*)pl)[i] = 0.f;
  if (tid < 36) wsm[tid / 9][tid % 9] = wpe[((tid / 9) * 256 + co) * 9 + tid % 9];
  __syncthreads();
  for (int i = tid; i < 4 * 1024; i += 256) {
    int p = i >> 10, n = i & 1023;
    int h = n >> 5, ww = n & 31;
    pl[p][(h + 1) * 34 + (ww + 1)] =
        x[(((size_t)b * 256 + co) * 4 + p) * 1024 + n];
  }
  __syncthreads();
  for (int n = tid; n < 1024; n += 256) {
    int h = n >> 5, ww = n & 31;
    float in[4][9];
#pragma unroll
    for (int p = 0; p < 4; ++p)
#pragma unroll
      for (int t = 0; t < 9; ++t)
        in[p][t] = pl[p][(h + t / 3) * 34 + (ww + t % 3)];
#pragma unroll
    for (int q = 0; q < 4; ++q) {
      float acc = bpe[q * 256 + co];
#pragma unroll
      for (int p = 0; p < 4; ++p) {
        int idx = d_IDX[q * 4 + p];
        float s = d_SGN[q * 4 + p];
        float sub = 0.f;
#pragma unroll
        for (int t = 0; t < 9; ++t) sub += in[p][t] * wsm[idx][t];
        acc += s * sub;
      }
      pe[(((size_t)b * 256 + co) * 4 + q) * 1024 + n] = acc;
    }
  }
}

// ---------------------------------------------------------------------------
// proj GEMM: tile = 256 (bn) x 128 (q,o). Grid 32x8 = 256 blocks.
// ---------------------------------------------------------------------------
__global__ __launch_bounds__(512, 2) void gemm_proj_mfma(
    const u16* __restrict__ AO, const u16* __restrict__ weffP,
    const float* __restrict__ bproj, const float* __restrict__ pe,
    float* __restrict__ out) {
  __shared__ u16 smem[3 * 384 * 64];  // 144 KB ring
  int n0 = blockIdx.x * 256;
  int m0 = blockIdx.y * 128;
  int tid = threadIdx.x;
  f32x4 acc[4][4];
#pragma unroll
  for (int i = 0; i < 4; ++i)
#pragma unroll
    for (int j = 0; j < 4; ++j) acc[i][j] = (f32x4){0.f, 0.f, 0.f, 0.f};
  gemm_core8<128, 256>(weffP + (size_t)m0 * 1024, AO + (size_t)n0 * 1024,
                       smem, smem + 3 * 128 * 64, tid, acc);

  int w = tid >> 6, lane = tid & 63, l16 = lane & 15, quad = lane >> 4;
  int wm = w >> 2, wn = w & 3;
#pragma unroll
  for (int i = 0; i < 4; ++i) {
#pragma unroll
    for (int r = 0; r < 4; ++r) {
      int mrow = m0 + wm * 64 + i * 16 + quad * 4 + r;
      int q = mrow >> 8, o = mrow & 255;
      float bias = bproj[mrow];
#pragma unroll
      for (int j = 0; j < 4; ++j) {
        int n = n0 + wn * 64 + j * 16 + l16;
        int b = n >> 10, npos = n & 1023;
        size_t oidx = (((size_t)b * 256 + o) * 4 + q) * 1024 + npos;
        out[oidx] = pe[oidx] + acc[i][j][r] + bias;
      }
    }
  }
}

// ---------------------------------------------------------------------------
extern "C" void kernel_launch(void* const* d_in, const int* in_sizes, int n_in,
                              void* d_out, int out_size, void* d_ws,
                              size_t ws_size, hipStream_t stream) {
  const float* x      = (const float*)d_in[0];
  const float* w_qkv  = (const float*)d_in[1];
  const float* b_qkv  = (const float*)d_in[2];
  const float* w_proj = (const float*)d_in[3];
  const float* b_proj = (const float*)d_in[4];
  const float* w_pe   = (const float*)d_in[5];
  const float* b_pe   = (const float*)d_in[6];
  float* out = (float*)d_out;

  u16* ws = (u16*)d_ws;
  u16* weffQ = ws;                                   // 3072*1024
  u16* weffP = weffQ + (size_t)H3 * DIM;             // 1024*1024
  u16* Ax    = weffP + (size_t)DIM * DIM;            // 8192*1024
  u16* Qb    = Ax + (size_t)MM * DIM;                // 64*1024*128
  u16* Kb    = Qb + (size_t)BB * NHD * NN * DD;      // 64*1024*128
  u16* VbT   = Kb + (size_t)BB * NHD * NN * DD;      // 64*128*1024
  u16* AO    = VbT + (size_t)BB * NHD * DD * NN;     // 8192*1024
  float* PE  = (float*)(AO + (size_t)MM * DIM);      // 8192*1024 fp32
  u16* OP    = (u16*)(PE + (size_t)MM * DIM);        // 2*64*1024*128 bf16
  float* LS  = (float*)(OP + (size_t)2 * 64 * NN * DD);  // 2*64*1024 fp32
  // total ~160 MB scratch

  hipLaunchKernelGGL(prep_weff, dim3(4096), dim3(256), 0, stream,
                     w_qkv, w_proj, weffQ, weffP);
  hipLaunchKernelGGL(prep_x, dim3(512), dim3(256), 0, stream, x, Ax);
  hipLaunchKernelGGL(gemm_qkv_mfma, dim3(MM / 256, H3 / 128), dim3(512), 0,
                     stream, Ax, weffQ, b_qkv, Qb, Kb, VbT);
  hipLaunchKernelGGL(attn_mfma, dim3(1024), dim3(256), 0, stream,
                     Qb, Kb, VbT, OP, LS);
  hipLaunchKernelGGL(attn_merge, dim3((64 * NN * DD) / (256 * 4)), dim3(256),
                     0, stream, OP, LS, AO);
  hipLaunchKernelGGL(qdwconv_kernel, dim3(BB * 256), dim3(256), 0, stream,
                     x, w_pe, b_pe, PE);
  hipLaunchKernelGGL(gemm_proj_mfma, dim3(MM / 256, DIM / 128), dim3(512), 0,
                     stream, AO, weffP, b_proj, PE, out);
}

// Round 8
// 288.784 us; speedup vs baseline: 1.2532x; 1.1745x over previous
//
#include <hip/hip_runtime.h>
#include <hip/hip_bf16.h>

typedef unsigned short u16;
typedef float f32x4 __attribute__((ext_vector_type(4)));
typedef __bf16 bf16x8 __attribute__((ext_vector_type(8)));
typedef __bf16 bf16x4 __attribute__((ext_vector_type(4)));
typedef unsigned short su8v __attribute__((ext_vector_type(8)));
typedef unsigned short su4v __attribute__((ext_vector_type(4)));
typedef short s16x4 __attribute__((ext_vector_type(4)));

#define BB 8
#define NHD 8
#define DD 128
#define NN 1024
#define DIM 1024
#define H3 3072
#define MM 8192
// scale * log2(e), folded into Q weights so softmax is exp2(raw dot)
#define QSC (0.08838834764831845f * 1.4426950408889634f)

__constant__ int   d_IDX[16] = {0,1,2,3, 1,0,3,2, 2,3,0,1, 3,2,1,0};
__constant__ float d_SGN[16] = {1.f,-1.f,-1.f,-1.f, 1.f,1.f,1.f,-1.f,
                                1.f,-1.f,1.f,1.f,  1.f,1.f,-1.f,1.f};

__device__ __forceinline__ f32x4 mfma16(su8v a, su8v b, f32x4 c) {
  return __builtin_amdgcn_mfma_f32_16x16x32_bf16(
      __builtin_bit_cast(bf16x8, a), __builtin_bit_cast(bf16x8, b), c, 0, 0, 0);
}
// 16x16x16 bf16 MFMA (K=16): A/B are 4 bf16 (2 VGPRs). Used for PV so the
// QK^T output registers feed PV directly (lane: m=l16, k=quad*4+e).
__device__ __forceinline__ f32x4 mfma16h(su4v a, su4v b, f32x4 c) {
#if __has_builtin(__builtin_amdgcn_mfma_f32_16x16x16_bf16)
  return __builtin_amdgcn_mfma_f32_16x16x16_bf16(
      __builtin_bit_cast(bf16x4, a), __builtin_bit_cast(bf16x4, b), c, 0, 0, 0);
#elif __has_builtin(__builtin_amdgcn_mfma_f32_16x16x16bf16_1k)
  return __builtin_amdgcn_mfma_f32_16x16x16bf16_1k(
      __builtin_bit_cast(s16x4, a), __builtin_bit_cast(s16x4, b), c, 0, 0, 0);
#else
  f32x4 d = c;
  asm("v_mfma_f32_16x16x16_bf16 %0, %1, %2, %0" : "+v"(d) : "v"(a), "v"(b));
  return d;
#endif
}
__device__ __forceinline__ u16 f2b(float f) {  // RNE
  unsigned int u = __builtin_bit_cast(unsigned int, f);
  u += 0x7fffu + ((u >> 16) & 1u);
  return (u16)(u >> 16);
}
__device__ __forceinline__ float b2f(u16 v) {
  unsigned int u = ((unsigned int)v) << 16;
  return __builtin_bit_cast(float, u);
}
typedef const __attribute__((address_space(1))) unsigned int* gas_t;
typedef __attribute__((address_space(3))) unsigned int* las_t;
__device__ __forceinline__ void gll16(const u16* g, u16* l) {
  __builtin_amdgcn_global_load_lds((gas_t)g, (las_t)l, 16, 0, 0);
}

// ---------------------------------------------------------------------------
// prep_weff: effective weights [out_row][in_col] bf16; Q-rows pre-scaled by QSC
// ---------------------------------------------------------------------------
__global__ __launch_bounds__(256) void prep_weff(
    const float* __restrict__ wqkv, const float* __restrict__ wproj,
    u16* __restrict__ weffQ, u16* __restrict__ weffP) {
  int tid = blockIdx.x * 256 + threadIdx.x;
  int stride = gridDim.x * 256;
  for (int i = tid; i < H3 * DIM; i += stride) {
    int row = i >> 10, col = i & 1023;
    int q = row / 768, o = row - q * 768;
    int p = col >> 8, c = col & 255;
    float v = d_SGN[q * 4 + p] * wqkv[(d_IDX[q * 4 + p] * 768 + o) * 256 + c];
    if (o < 256) v *= QSC;  // Q rows
    weffQ[i] = f2b(v);
  }
  for (int i = tid; i < DIM * DIM; i += stride) {
    int row = i >> 10, col = i & 1023;
    int q = row >> 8, o = row & 255;
    int p = col >> 8, c = col & 255;
    weffP[i] = f2b(d_SGN[q * 4 + p] * wproj[(d_IDX[q * 4 + p] * 256 + o) * 256 + c]);
  }
}

// ---------------------------------------------------------------------------
// prep_x: x (B,Cc,4,N) fp32 -> Ax bf16 [8192 (b,n)][1024 (p,c)].
// LDS transpose, layout T[n][pc] stride 264 u16 (16B-aligned su8v reads).
// ---------------------------------------------------------------------------
__global__ __launch_bounds__(256) void prep_x(
    const float* __restrict__ x, u16* __restrict__ Ax) {
  __shared__ u16 T[64 * 264];  // [n][pc], stride 264
  int blk = blockIdx.x;
  int nc = blk & 15;
  int cc = (blk >> 4) & 3;
  int b = blk >> 6;
  int n0 = nc * 64, c0 = cc * 64;
  int tid = threadIdx.x;
  int nseg = tid & 15, rq = tid >> 4;  // rq 0..15
#pragma unroll
  for (int pass = 0; pass < 16; ++pass) {
    int rr = pass * 16 + rq;  // pc local 0..255: p = rr>>6, c = rr&63
    int p = rr >> 6, c = rr & 63;
    float4 f = *(const float4*)(x + (((size_t)(b * 256 + c0 + c)) * 4 + p) * 1024 +
                                n0 + nseg * 4);
    T[(nseg * 4 + 0) * 264 + rr] = f2b(f.x);
    T[(nseg * 4 + 1) * 264 + rr] = f2b(f.y);
    T[(nseg * 4 + 2) * 264 + rr] = f2b(f.z);
    T[(nseg * 4 + 3) * 264 + rr] = f2b(f.w);
  }
  __syncthreads();
  int nl = tid >> 5, lc = tid & 31;
#pragma unroll
  for (int pass = 0; pass < 8; ++pass) {
    int n = pass * 8 + nl;
    su8v v = *(const su8v*)(&T[n * 264 + lc * 8]);
    int pcl = lc * 8;
    *(su8v*)(Ax + (size_t)(b * 1024 + n0 + n) * 1024 + (pcl >> 6) * 256 + c0 +
             (pcl & 63)) = v;
  }
}

// ---------------------------------------------------------------------------
// 8-wave GEMM core, ONE barrier per K-tile + counted vmcnt, free-running
// waves. Tile BM x BN (BM+BN == 384), BK=64, 512 threads = 8 waves of 64x64.
// 3-slot LDS ring; loads for 2 future tiles stay in flight across barriers.
// LDS rows 64 u16 = 8 x 16B blocks, XOR-swizzled (blk ^= row&7); global
// source pre-swizzled identically so gll's linear LDS write lands right.
// ---------------------------------------------------------------------------
template <int BM, int BN>
__device__ __forceinline__ void gemm_core8(
    const u16* __restrict__ Ag, const u16* __restrict__ Bg,
    u16* As, u16* Bs, int tid, f32x4 (&acc)[4][4]) {
  constexpr int WN = BN / 64;
  constexpr int AC = BM / 64;
  constexpr int BC = BN / 64;
  constexpr int NT = 16;  // K = 1024 / BK(64)
  int w = tid >> 6, lane = tid & 63, l16 = lane & 15, quad = lane >> 4;
  int wm = w / WN, wn = w % WN;
  int x7 = l16 & 7;
  int srow = lane >> 3;
  int sblk = (lane & 7) ^ srow;

  auto STAGE_A = [&](int tt, int bs) {
#pragma unroll
    for (int c = 0; c < AC; ++c) {
      int r0 = c * 64 + w * 8;
      gll16(Ag + (size_t)(r0 + srow) * 1024 + tt * 64 + sblk * 8,
            As + (size_t)bs * (BM * 64) + r0 * 64);
    }
  };
  auto STAGE_B = [&](int tt, int bs) {
#pragma unroll
    for (int c = 0; c < BC; ++c) {
      int r0 = c * 64 + w * 8;
      gll16(Bg + (size_t)(r0 + srow) * 1024 + tt * 64 + sblk * 8,
            Bs + (size_t)bs * (BN * 64) + r0 * 64);
    }
  };

  STAGE_A(0, 0); STAGE_B(0, 0);
  STAGE_A(1, 1); STAGE_B(1, 1);
  asm volatile("s_waitcnt vmcnt(6)" ::: "memory");
  __builtin_amdgcn_s_barrier();

  int cur = 0, nxt = 1, stg = 2;
  for (int t = 0; t < NT; ++t) {
    const u16* At = As + (size_t)cur * (BM * 64);
    const u16* Bt = Bs + (size_t)cur * (BN * 64);
#pragma unroll
    for (int kk = 0; kk < 2; ++kk) {
      su8v af[4], bf[4];
#pragma unroll
      for (int i = 0; i < 4; ++i)
        af[i] = *(const su8v*)(At + (wm * 64 + i * 16 + l16) * 64 +
                               ((kk * 4 + quad) ^ x7) * 8);
#pragma unroll
      for (int j = 0; j < 4; ++j)
        bf[j] = *(const su8v*)(Bt + (wn * 64 + j * 16 + l16) * 64 +
                               ((kk * 4 + quad) ^ x7) * 8);
      if (t + 2 < NT) {
        if (kk == 0) STAGE_A(t + 2, stg);
        else         STAGE_B(t + 2, stg);
      }
      __builtin_amdgcn_s_setprio(1);
#pragma unroll
      for (int i = 0; i < 4; ++i)
#pragma unroll
        for (int j = 0; j < 4; ++j)
          acc[i][j] = mfma16(af[i], bf[j], acc[i][j]);
      __builtin_amdgcn_s_setprio(0);
    }
    if (t < NT - 2)       asm volatile("s_waitcnt vmcnt(6)" ::: "memory");
    else if (t == NT - 2) asm volatile("s_waitcnt vmcnt(0)" ::: "memory");
    asm volatile("" ::: "memory");
    __builtin_amdgcn_s_barrier();
    asm volatile("" ::: "memory");
    int tmp = cur; cur = nxt; nxt = stg; stg = tmp;
  }
}

// ---------------------------------------------------------------------------
// QKV GEMM: tile = 256 (bn) x 128 (chan). Grid 32x24 = 768 blocks.
// ---------------------------------------------------------------------------
__global__ __launch_bounds__(512, 2) void gemm_qkv_mfma(
    const u16* __restrict__ Ax, const u16* __restrict__ weffQ,
    const float* __restrict__ bqkv,
    u16* __restrict__ Qb, u16* __restrict__ Kb, u16* __restrict__ VbT) {
  __shared__ u16 smem[3 * 384 * 64];  // 144 KB: 3-slot ring, A tile + B tile
  int bn0 = blockIdx.x * 256;
  int col0 = blockIdx.y * 128;
  int q = col0 / 768;
  int off = col0 - q * 768;
  int sel = off >> 8;  // 0=Q 1=K 2=V (uniform)
  int head = (q * 256 + (off & 255)) >> 7;
  int tid = threadIdx.x;
  int w = tid >> 6, lane = tid & 63, l16 = lane & 15, quad = lane >> 4;
  f32x4 acc[4][4];
#pragma unroll
  for (int i = 0; i < 4; ++i)
#pragma unroll
    for (int j = 0; j < 4; ++j) acc[i][j] = (f32x4){0.f, 0.f, 0.f, 0.f};

  if (sel == 2) {
    // ---- V: m=bn (256), n=chan (128) ----
    gemm_core8<256, 128>(Ax + (size_t)bn0 * 1024, weffQ + (size_t)col0 * 1024,
                         smem, smem + 3 * 256 * 64, tid, acc);
    int wm = w >> 1, wn = w & 1;
#pragma unroll
    for (int j = 0; j < 4; ++j) {
      int dl = wn * 64 + j * 16 + l16;
      float bias = bqkv[col0 + dl];
#pragma unroll
      for (int i = 0; i < 4; ++i) {
        int m = bn0 + wm * 64 + i * 16 + quad * 4;
        int b = m >> 10, npos = m & 1023;
        int bh = b * NHD + head;
        su4v pk;
#pragma unroll
        for (int r = 0; r < 4; ++r) pk[r] = f2b(acc[i][j][r] + bias);
        *(su4v*)(VbT + ((size_t)bh * DD + dl) * NN + npos) = pk;
      }
    }
  } else {
    // ---- Q/K: m=chan (128), n=bn (256) ----
    gemm_core8<128, 256>(weffQ + (size_t)col0 * 1024, Ax + (size_t)bn0 * 1024,
                         smem, smem + 3 * 128 * 64, tid, acc);
    int wm = w >> 2, wn = w & 3;
    u16* dst = (sel == 0) ? Qb : Kb;
    float sc = (sel == 0) ? (float)QSC : 1.0f;
#pragma unroll
    for (int i = 0; i < 4; ++i) {
      int dbase = wm * 64 + i * 16 + quad * 4;
      float4 b4 = *(const float4*)(bqkv + col0 + dbase);
#pragma unroll
      for (int j = 0; j < 4; ++j) {
        int n = bn0 + wn * 64 + j * 16 + l16;
        int b = n >> 10, npos = n & 1023;
        int bh = b * NHD + head;
        su4v pk;
        pk[0] = f2b(acc[i][j][0] + b4.x * sc);
        pk[1] = f2b(acc[i][j][1] + b4.y * sc);
        pk[2] = f2b(acc[i][j][2] + b4.z * sc);
        pk[3] = f2b(acc[i][j][3] + b4.w * sc);
        *(su4v*)(dst + ((size_t)bh * NN + npos) * DD + dbase) = pk;
      }
    }
  }
}

// ---------------------------------------------------------------------------
// Flash attention, split-K x2: 1024 blocks = half(2) x qt(8) x bh(64).
// 128 q x 512 keys per block. Single-buffered K/V (32 KB). In-register P:
// QK^T computes S^T per 16-key slice j (lane: q=l16, key=j*16+quad*4+r),
// which IS the A-fragment of 16x16x16 MFMA; exp2+pack feeds PV directly.
// j-loop fused (QK slice -> exp2 -> PV slice) so pk recycles per slice.
// NO __launch_bounds__ min-waves arg: natural alloc ~140-150 unified regs,
// no spill. (256,4) capped at 128 -> spill collapse (round 6, 160MB scratch);
// (256,3) still spilled ~56 dwords/thread (round 7, 58MB scratch). Round-5
// showed the no-pressure allocation is exactly clean (WRITE=33.3MB).
// ---------------------------------------------------------------------------
__global__ __launch_bounds__(256) void attn_mfma(
    const u16* __restrict__ Qb, const u16* __restrict__ Kb,
    const u16* __restrict__ VbT, u16* __restrict__ OP,
    float* __restrict__ LS) {
  __shared__ u16 Ks[64 * 128];  // 16 KB, xor-swizzled 16B blocks
  __shared__ u16 Vt[128 * 64];  // 16 KB, xor-swizzled 16B blocks
  int blk = blockIdx.x;
  int bh = blk & 63;  // low bits -> blk%8 == bh%8 (same XCD for K/V L2 reuse)
  int rest = blk >> 6;
  int qt = rest & 7;
  int half = rest >> 3;
  int n0 = qt * 128;
  int tid = threadIdx.x;
  int w = tid >> 6, lane = tid & 63, l16 = lane & 15, quad = lane >> 4;
  const u16* Qg = Qb + ((size_t)bh * NN + n0) * DD;
  const u16* Kg = Kb + (size_t)bh * NN * DD;
  const u16* Vg = VbT + (size_t)bh * DD * NN;
  int x7 = l16 & 7;

  su8v qreg[2][4];  // B-fragment: n=q (l16), k=d
#pragma unroll
  for (int mi = 0; mi < 2; ++mi)
#pragma unroll
    for (int ch = 0; ch < 4; ++ch)
      qreg[mi][ch] = *(const su8v*)(Qg + (size_t)(w * 32 + mi * 16 + l16) * DD +
                                    ch * 32 + quad * 8);

  float ls[2] = {0.f, 0.f};
  f32x4 accO[2][8];
#pragma unroll
  for (int mi = 0; mi < 2; ++mi)
#pragma unroll
    for (int dt = 0; dt < 8; ++dt) accO[mi][dt] = (f32x4){0.f, 0.f, 0.f, 0.f};

  for (int kt = 0; kt < 8; ++kt) {
    int c0 = half * 512 + kt * 64;
    __syncthreads();
#pragma unroll
    for (int t = 0; t < 4; ++t) {
      int ci = w * 4 + t;
      // K: rows of 256B = 16 x 16B blocks; block low-3-bits xor row&7
      int krow = ci * 4 + (lane >> 4);
      int kblk = (lane & 15) ^ (krow & 7);
      gll16(Kg + (size_t)(c0 + krow) * DD + kblk * 8, Ks + ci * 512);
      // V^T: rows of 128B = 8 x 16B blocks; xor-swizzled
      int dv = ci * 8 + (lane >> 3);
      int vblk = (lane & 7) ^ (dv & 7);
      gll16(Vg + (size_t)dv * NN + c0 + vblk * 8, Vt + ci * 512);
    }
    __syncthreads();

    // fused per-16-key-slice: QK^T -> exp2/pack -> PV (pk recycles per j)
#pragma unroll
    for (int j = 0; j < 4; ++j) {
      f32x4 s0 = (f32x4){0.f, 0.f, 0.f, 0.f};
      f32x4 s1 = (f32x4){0.f, 0.f, 0.f, 0.f};
#pragma unroll
      for (int ch = 0; ch < 4; ++ch) {
        su8v kf = *(const su8v*)(Ks + (j * 16 + l16) * 128 +
                                 (((ch * 4 + quad) ^ x7) * 8));
        s0 = mfma16(kf, qreg[0][ch], s0);
        s1 = mfma16(kf, qreg[1][ch], s1);
      }
      su4v p0, p1;
#pragma unroll
      for (int r = 0; r < 4; ++r) {
        float pa = __builtin_exp2f(s0[r]);
        ls[0] += pa;
        p0[r] = (u16)(__builtin_bit_cast(unsigned int, pa) >> 16);
        float pb = __builtin_exp2f(s1[r]);
        ls[1] += pb;
        p1[r] = (u16)(__builtin_bit_cast(unsigned int, pb) >> 16);
      }
#pragma unroll
      for (int dt = 0; dt < 8; ++dt) {
        su4v vf = *(const su4v*)(Vt + (dt * 16 + l16) * 64 +
                                 ((((j * 2 + (quad >> 1)) ^ x7) << 3) +
                                  (quad & 1) * 4));
        accO[0][dt] = mfma16h(p0, vf, accO[0][dt]);
        accO[1][dt] = mfma16h(p1, vf, accO[1][dt]);
      }
    }
  }

  // row-sum: reduce over quad lanes (bits 4,5) -> all lanes hold full sum
#pragma unroll
  for (int mi = 0; mi < 2; ++mi) {
    float s = ls[mi];
    s += __shfl_xor(s, 16, 64);
    s += __shfl_xor(s, 32, 64);
    ls[mi] = s;
  }
  size_t hb = (size_t)(half * 64 + bh);
  if (quad == 0) {
#pragma unroll
    for (int mi = 0; mi < 2; ++mi)
      LS[hb * NN + n0 + w * 32 + mi * 16 + l16] = ls[mi];
  }
  // store unnormalized O partial (bf16)
#pragma unroll
  for (int mi = 0; mi < 2; ++mi)
#pragma unroll
    for (int r = 0; r < 4; ++r) {
      int row = w * 32 + mi * 16 + quad * 4 + r;
      size_t base = (hb * NN + n0 + row) * DD;
#pragma unroll
      for (int dt = 0; dt < 8; ++dt)
        OP[base + dt * 16 + l16] = f2b(accO[mi][dt][r]);
    }
}

// ---------------------------------------------------------------------------
// merge: AO[b,n][head*128+d] = (O0 + O1) / (l0 + l1)
// ---------------------------------------------------------------------------
__global__ __launch_bounds__(256) void attn_merge(
    const u16* __restrict__ OP, const float* __restrict__ LS,
    u16* __restrict__ AO) {
  size_t idx = (size_t)blockIdx.x * 256 + threadIdx.x;  // 4-elem chunk id
  size_t e = idx * 4;
  int d = (int)(e & 127);
  size_t bhn = e >> 7;  // bh*1024 + n
  su4v a = *(const su4v*)(OP + bhn * DD + d);
  su4v b = *(const su4v*)(OP + (size_t)64 * NN * DD + bhn * DD + d);
  float inv = 1.0f / (LS[bhn] + LS[bhn + 64 * NN]);
  int bh = (int)(bhn >> 10), n = (int)(bhn & 1023);
  int bb = bh >> 3, head = bh & 7;
  su4v o;
#pragma unroll
  for (int r = 0; r < 4; ++r) o[r] = f2b((b2f(a[r]) + b2f(b[r])) * inv);
  *(su4v*)(AO + ((size_t)(bb * 1024 + n) * 1024) + head * 128 + d) = o;
}

// ---------------------------------------------------------------------------
// quaternion depthwise 3x3 conv (fp32) — writes PE term into workspace
// ---------------------------------------------------------------------------
__global__ __launch_bounds__(256) void qdwconv_kernel(
    const float* __restrict__ x, const float* __restrict__ wpe,
    const float* __restrict__ bpe, float* __restrict__ pe) {
  int blk = blockIdx.x;
  int co = blk & 255;
  int b = blk >> 8;
  __shared__ float pl[4][34 * 34];
  __shared__ float wsm[4][9];
  int tid = threadIdx.x;
  for (int i = tid; i < 4 * 34 * 34; i += 256) ((float*)pl)[i] = 0.f;
  if (tid < 36) wsm[tid / 9][tid % 9] = wpe[((tid / 9) * 256 + co) * 9 + tid % 9];
  __syncthreads();
  for (int i = tid; i < 4 * 1024; i += 256) {
    int p = i >> 10, n = i & 1023;
    int h = n >> 5, ww = n & 31;
    pl[p][(h + 1) * 34 + (ww + 1)] =
        x[(((size_t)b * 256 + co) * 4 + p) * 1024 + n];
  }
  __syncthreads();
  for (int n = tid; n < 1024; n += 256) {
    int h = n >> 5, ww = n & 31;
    float in[4][9];
#pragma unroll
    for (int p = 0; p < 4; ++p)
#pragma unroll
      for (int t = 0; t < 9; ++t)
        in[p][t] = pl[p][(h + t / 3) * 34 + (ww + t % 3)];
#pragma unroll
    for (int q = 0; q < 4; ++q) {
      float acc = bpe[q * 256 + co];
#pragma unroll
      for (int p = 0; p < 4; ++p) {
        int idx = d_IDX[q * 4 + p];
        float s = d_SGN[q * 4 + p];
        float sub = 0.f;
#pragma unroll
        for (int t = 0; t < 9; ++t) sub += in[p][t] * wsm[idx][t];
        acc += s * sub;
      }
      pe[(((size_t)b * 256 + co) * 4 + q) * 1024 + n] = acc;
    }
  }
}

// ---------------------------------------------------------------------------
// proj GEMM: tile = 256 (bn) x 128 (q,o). Grid 32x8 = 256 blocks.
// ---------------------------------------------------------------------------
__global__ __launch_bounds__(512, 2) void gemm_proj_mfma(
    const u16* __restrict__ AO, const u16* __restrict__ weffP,
    const float* __restrict__ bproj, const float* __restrict__ pe,
    float* __restrict__ out) {
  __shared__ u16 smem[3 * 384 * 64];  // 144 KB ring
  int n0 = blockIdx.x * 256;
  int m0 = blockIdx.y * 128;
  int tid = threadIdx.x;
  f32x4 acc[4][4];
#pragma unroll
  for (int i = 0; i < 4; ++i)
#pragma unroll
    for (int j = 0; j < 4; ++j) acc[i][j] = (f32x4){0.f, 0.f, 0.f, 0.f};
  gemm_core8<128, 256>(weffP + (size_t)m0 * 1024, AO + (size_t)n0 * 1024,
                       smem, smem + 3 * 128 * 64, tid, acc);

  int w = tid >> 6, lane = tid & 63, l16 = lane & 15, quad = lane >> 4;
  int wm = w >> 2, wn = w & 3;
#pragma unroll
  for (int i = 0; i < 4; ++i) {
#pragma unroll
    for (int r = 0; r < 4; ++r) {
      int mrow = m0 + wm * 64 + i * 16 + quad * 4 + r;
      int q = mrow >> 8, o = mrow & 255;
      float bias = bproj[mrow];
#pragma unroll
      for (int j = 0; j < 4; ++j) {
        int n = n0 + wn * 64 + j * 16 + l16;
        int b = n >> 10, npos = n & 1023;
        size_t oidx = (((size_t)b * 256 + o) * 4 + q) * 1024 + npos;
        out[oidx] = pe[oidx] + acc[i][j][r] + bias;
      }
    }
  }
}

// ---------------------------------------------------------------------------
extern "C" void kernel_launch(void* const* d_in, const int* in_sizes, int n_in,
                              void* d_out, int out_size, void* d_ws,
                              size_t ws_size, hipStream_t stream) {
  const float* x      = (const float*)d_in[0];
  const float* w_qkv  = (const float*)d_in[1];
  const float* b_qkv  = (const float*)d_in[2];
  const float* w_proj = (const float*)d_in[3];
  const float* b_proj = (const float*)d_in[4];
  const float* w_pe   = (const float*)d_in[5];
  const float* b_pe   = (const float*)d_in[6];
  float* out = (float*)d_out;

  u16* ws = (u16*)d_ws;
  u16* weffQ = ws;                                   // 3072*1024
  u16* weffP = weffQ + (size_t)H3 * DIM;             // 1024*1024
  u16* Ax    = weffP + (size_t)DIM * DIM;            // 8192*1024
  u16* Qb    = Ax + (size_t)MM * DIM;                // 64*1024*128
  u16* Kb    = Qb + (size_t)BB * NHD * NN * DD;      // 64*1024*128
  u16* VbT   = Kb + (size_t)BB * NHD * NN * DD;      // 64*128*1024
  u16* AO    = VbT + (size_t)BB * NHD * DD * NN;     // 8192*1024
  float* PE  = (float*)(AO + (size_t)MM * DIM);      // 8192*1024 fp32
  u16* OP    = (u16*)(PE + (size_t)MM * DIM);        // 2*64*1024*128 bf16
  float* LS  = (float*)(OP + (size_t)2 * 64 * NN * DD);  // 2*64*1024 fp32
  // total ~160 MB scratch

  hipLaunchKernelGGL(prep_weff, dim3(4096), dim3(256), 0, stream,
                     w_qkv, w_proj, weffQ, weffP);
  hipLaunchKernelGGL(prep_x, dim3(512), dim3(256), 0, stream, x, Ax);
  hipLaunchKernelGGL(gemm_qkv_mfma, dim3(MM / 256, H3 / 128), dim3(512), 0,
                     stream, Ax, weffQ, b_qkv, Qb, Kb, VbT);
  hipLaunchKernelGGL(attn_mfma, dim3(1024), dim3(256), 0, stream,
                     Qb, Kb, VbT, OP, LS);
  hipLaunchKernelGGL(attn_merge, dim3((64 * NN * DD) / (256 * 4)), dim3(256),
                     0, stream, OP, LS, AO);
  hipLaunchKernelGGL(qdwconv_kernel, dim3(BB * 256), dim3(256), 0, stream,
                     x, w_pe, b_pe, PE);
  hipLaunchKernelGGL(gemm_proj_mfma, dim3(MM / 256, DIM / 128), dim3(512), 0,
                     stream, AO, weffP, b_proj, PE, out);
}